// Round 19
// baseline (238.519 us; speedup 1.0000x reference)
//
#include <hip/hip_runtime.h>
#include <hip/hip_bf16.h>

typedef __bf16 bf16x8 __attribute__((ext_vector_type(8)));
typedef __bf16 bf16x4 __attribute__((ext_vector_type(4)));
typedef float  f32x4  __attribute__((ext_vector_type(4)));

#define MFMA16(a, b, c) __builtin_amdgcn_mfma_f32_16x16x32_bf16((a), (b), (c), 0, 0, 0)
#define GLD16(g, l)                                                              \
    __builtin_amdgcn_global_load_lds(                                            \
        (const __attribute__((address_space(1))) void*)(g),                      \
        (__attribute__((address_space(3))) void*)(l), 16, 0, 0)

// ------------- fused fp32 -> bf16 convert for all three tensors (1 launch) ------
__global__ __launch_bounds__(256) void cvt3_f32_bf16(const float* __restrict__ a, __bf16* __restrict__ oa, int na,
                                                     const float* __restrict__ b, __bf16* __restrict__ ob, int nb,
                                                     const float* __restrict__ c, __bf16* __restrict__ oc, int nc) {
    const int stride = gridDim.x * blockDim.x * 4;
    const int start = (blockIdx.x * blockDim.x + threadIdx.x) * 4;
    for (int i = start; i < na; i += stride) {
        float4 v = *(const float4*)(a + i);
        bf16x4 o; o[0] = (__bf16)v.x; o[1] = (__bf16)v.y; o[2] = (__bf16)v.z; o[3] = (__bf16)v.w;
        *(bf16x4*)(oa + i) = o;
    }
    for (int i = start; i < nb; i += stride) {
        float4 v = *(const float4*)(b + i);
        bf16x4 o; o[0] = (__bf16)v.x; o[1] = (__bf16)v.y; o[2] = (__bf16)v.z; o[3] = (__bf16)v.w;
        *(bf16x4*)(ob + i) = o;
    }
    for (int i = start; i < nc; i += stride) {
        float4 v = *(const float4*)(c + i);
        bf16x4 o; o[0] = (__bf16)v.x; o[1] = (__bf16)v.y; o[2] = (__bf16)v.z; o[3] = (__bf16)v.w;
        *(bf16x4*)(oc + i) = o;
    }
}

// ---------------- QKV GEMM (m97 + XCD swizzle + fragment-native K/V epilogues) ---
// Q pre-scaled by 0.125 * log2(e) = 0.18033688 so attention can use exp2 directly.
__global__ __launch_bounds__(256, 2) void qkv_gemm(const __bf16* __restrict__ X,
                                                   const __bf16* __restrict__ W,
                                                   const float* __restrict__ bias,
                                                   __bf16* __restrict__ Qo,
                                                   __bf16* __restrict__ Kf,
                                                   __bf16* __restrict__ Vf) {
    const int KD = 1024;
    __shared__ __align__(16) char smem[34816];   // As 8K | Bs 8K ; V-epilogue reuses
    __bf16* As = (__bf16*)smem;
    __bf16* Bs = (__bf16*)(smem + 8192);
    const int tid = threadIdx.x;
    const int lane = tid & 63, w = tid >> 6;
    const int lr = lane & 15, lg = lane >> 4;
    const int orig = blockIdx.x;                       // 0..1535
    const int wgid = (orig & 7) * 192 + (orig >> 3);   // bijective (1536 % 8 == 0)
    const int row0 = (wgid & 63) * 128, col0 = (wgid >> 6) * 128;
    const int wrow = (w >> 1) * 64, wcol = (w & 1) * 64;
    f32x4 acc[4][4] = {};
    const int c0 = tid, c1 = tid + 256;
    const __bf16* ga0 = X + (size_t)(row0 + (c0 >> 2)) * KD + (c0 & 3) * 8;
    const __bf16* ga1 = X + (size_t)(row0 + (c1 >> 2)) * KD + (c1 & 3) * 8;
    const __bf16* gb0 = W + (size_t)(col0 + (c0 >> 2)) * KD + (c0 & 3) * 8;
    const __bf16* gb1 = W + (size_t)(col0 + (c1 >> 2)) * KD + (c1 & 3) * 8;
    for (int k0 = 0; k0 < KD; k0 += 32) {
        __syncthreads();
        GLD16(ga0 + k0, As + c0 * 8);
        GLD16(ga1 + k0, As + c1 * 8);
        GLD16(gb0 + k0, Bs + c0 * 8);
        GLD16(gb1 + k0, Bs + c1 * 8);
        __syncthreads();
        bf16x8 a[4], b[4];
#pragma unroll
        for (int mi = 0; mi < 4; mi++)
            a[mi] = *(const bf16x8*)&As[(wrow + mi * 16 + lr) * 32 + lg * 8];
#pragma unroll
        for (int ni = 0; ni < 4; ni++)
            b[ni] = *(const bf16x8*)&Bs[(wcol + ni * 16 + lr) * 32 + lg * 8];
#pragma unroll
        for (int mi = 0; mi < 4; mi++)
#pragma unroll
            for (int ni = 0; ni < 4; ni++)
                acc[mi][ni] = MFMA16(a[mi], b[ni], acc[mi][ni]);
    }

    if (col0 < 1024) {
        // Q section: direct stores, pre-scaled by 0.125*log2(e)
#pragma unroll
        for (int mi = 0; mi < 4; mi++)
#pragma unroll
            for (int ni = 0; ni < 4; ni++)
#pragma unroll
                for (int r = 0; r < 4; r++) {
                    int m = row0 + wrow + mi * 16 + lg * 4 + r;
                    int n = col0 + wcol + ni * 16 + lr;
                    float v = acc[mi][ni][r] + bias[n];
                    int b_ = m >> 11, t = m & 2047;
                    int c = n & 1023;
                    int bh = b_ * 16 + (c >> 6), d = c & 63;
                    Qo[(size_t)(bh * 2048 + t) * 64 + d] = (__bf16)(v * 0.18033688f);
                }
    } else if (col0 < 2048) {
        // K section: direct scatter to fragment-native Kf
#pragma unroll
        for (int mi = 0; mi < 4; mi++)
#pragma unroll
            for (int ni = 0; ni < 4; ni++)
#pragma unroll
                for (int r = 0; r < 4; r++) {
                    int m = row0 + wrow + mi * 16 + lg * 4 + r;
                    int n = col0 + wcol + ni * 16 + lr;
                    float v = acc[mi][ni][r] + bias[n];
                    int b_ = m >> 11, t = m & 2047;
                    int c = n & 1023;
                    int bh = b_ * 16 + (c >> 6), d = c & 63;
                    size_t flat = (((size_t)bh * 128 + (t >> 4)) * 2 + (d >> 5)) * 512
                                + (((d & 31) >> 3) * 16 + (t & 15)) * 8 + (d & 7);
                    Kf[flat] = (__bf16)v;
                }
    } else {
        // V section: LDS [ch][token] transpose -> coalesced 1KB stores to Vf
        __syncthreads();
        __bf16* vt = (__bf16*)smem;          // [128 ch][136] padded
#pragma unroll
        for (int mi = 0; mi < 4; mi++)
#pragma unroll
            for (int ni = 0; ni < 4; ni++) {
                int cl = wcol + ni * 16 + lr;
                int tl = wrow + mi * 16 + lg * 4;
                int n = col0 + cl;
                bf16x4 pk;
#pragma unroll
                for (int r = 0; r < 4; r++)
                    pk[r] = (__bf16)(acc[mi][ni][r] + bias[n]);
                *(bf16x4*)&vt[cl * 136 + tl] = pk;
            }
        __syncthreads();
        const int b_ = row0 >> 11, t_base = row0 & 2047;
        const int lane2 = tid & 63, w2 = tid >> 6;
        const int lr2 = lane2 & 15, lg2 = lane2 >> 4;
#pragma unroll
        for (int g = 0; g < 8; g++) {
            int group = g * 4 + w2;                      // 0..31
            int hh2 = group >> 4;
            int k32l = (group >> 2) & 3;
            int dt = group & 3;
            const __bf16* src = &vt[(hh2 * 64 + dt * 16 + lr2) * 136 + k32l * 32 + lg2 * 8];
            int c = (col0 & 1023) + hh2 * 64;
            int bh = b_ * 16 + (c >> 6);
            int kt32 = (t_base >> 5) + k32l;
            __bf16* dst = Vf + ((((size_t)bh * 64 + kt32) * 4 + dt) * 512) + lane2 * 8;
            *(bf16x8*)dst = *(const bf16x8*)src;
        }
    }
}

// ---------------- causal flash attention (dense K/V, KBLK=128) -------------------
// 512 blocks x 4 waves = 2048 uniform independent waves; wave owns q-tile pair
// {idx, 63-idx} = 17 k-tiles of 128 (vs 33 of 64): amortizes the measured ~1.2us
// fixed per-tile stall. Dense fragment-native K/V loads (r16). P goes through TWO
// proven-conflict-free [32][68] slabs (r13's conflict confound removed). exp2
// throughout (log2e folded into Q pre-scale). Diagonal-only masking.
__global__ __launch_bounds__(256) void attn_kernel(const __bf16* __restrict__ Q,
                                                   const __bf16* __restrict__ Kf,
                                                   const __bf16* __restrict__ Vf,
                                                   __bf16* __restrict__ ATT) {
    const int T = 2048, D = 64;
    __shared__ __align__(16) __bf16 plds[4][2][32][68];  // padded: conflict-free
    const int lane = threadIdx.x & 63, w = threadIdx.x >> 6;
    const int lr = lane & 15, lg = lane >> 4;
    const int orig = blockIdx.x;
    const int wgid = (orig & 7) * 64 + (orig >> 3);   // bijective XCD swizzle
    const int bh = wgid >> 3;                 // 8 blocks per bh
    const int idx = (wgid & 7) * 4 + w;       // 0..31
    const int b_ = bh >> 4, hh = bh & 15;
    const __bf16* Qp  = Q  + (size_t)bh * T * D;
    const __bf16* Kfp = Kf + (size_t)bh * 131072;   // 128 kt16 x 2 dk x 512
    const __bf16* Vfp = Vf + (size_t)bh * 131072;   // 64 kt32 x 4 dt x 512

    for (int ph = 0; ph < 2; ++ph) {
        const int j = ph ? 63 - idx : idx;
        const int qrow0 = j * 32;
        bf16x8 qa[2][2];
#pragma unroll
        for (int qt = 0; qt < 2; qt++)
#pragma unroll
            for (int dk = 0; dk < 2; dk++)
                qa[qt][dk] = *(const bf16x8*)(Qp + (size_t)(qrow0 + qt * 16 + lr) * D + dk * 32 + lg * 8);

        float mrow[2][4], lsum[2][4];
#pragma unroll
        for (int qt = 0; qt < 2; qt++)
#pragma unroll
            for (int r = 0; r < 4; r++) { mrow[qt][r] = -1e30f; lsum[qt][r] = 0.f; }
        f32x4 o[2][4] = {};

        const int nkb = (j >> 2) + 1;        // 128-wide k-tiles

        auto tileBody = [&](int kt0, bool masked) {
            const int kb = kt0 * 128;
            f32x4 s[2][8] = {};
            // QK in two register-reusing 64-halves (dense Kf loads)
            {
                bf16x8 kf[4][2];
#pragma unroll
                for (int kt = 0; kt < 4; kt++)
#pragma unroll
                    for (int dk = 0; dk < 2; dk++)
                        kf[kt][dk] = *(const bf16x8*)(Kfp + (((kt0 * 8 + kt) * 2 + dk) << 9) + lane * 8);
#pragma unroll
                for (int qt = 0; qt < 2; qt++)
#pragma unroll
                    for (int kt = 0; kt < 4; kt++)
#pragma unroll
                        for (int dk = 0; dk < 2; dk++)
                            s[qt][kt] = MFMA16(qa[qt][dk], kf[kt][dk], s[qt][kt]);
            }
            {
                bf16x8 kf[4][2];
#pragma unroll
                for (int kt = 0; kt < 4; kt++)
#pragma unroll
                    for (int dk = 0; dk < 2; dk++)
                        kf[kt][dk] = *(const bf16x8*)(Kfp + (((kt0 * 8 + 4 + kt) * 2 + dk) << 9) + lane * 8);
#pragma unroll
                for (int qt = 0; qt < 2; qt++)
#pragma unroll
                    for (int kt = 0; kt < 4; kt++)
#pragma unroll
                        for (int dk = 0; dk < 2; dk++)
                            s[qt][4 + kt] = MFMA16(qa[qt][dk], kf[kt][dk], s[qt][4 + kt]);
            }

            // (mask only on diagonal tile) + per-lane local max
            float lmax[2][4];
            int flag = 0;
#pragma unroll
            for (int qt = 0; qt < 2; qt++)
#pragma unroll
                for (int r = 0; r < 4; r++) {
                    const int qq = qrow0 + qt * 16 + lg * 4 + r;
                    float mt = -1e30f;
#pragma unroll
                    for (int kt = 0; kt < 8; kt++) {
                        float v = s[qt][kt][r];
                        if (masked) v = (kb + kt * 16 + lr <= qq) ? v : -1e30f;
                        s[qt][kt][r] = v;
                        mt = fmaxf(mt, v);
                    }
                    lmax[qt][r] = mt;
                    flag |= (mt > mrow[qt][r] + 8.0f) ? 1 : 0;
                }

            // defer-max (T13): full reduce + rescale only when some row grew > 8
            if (__any(flag)) {
#pragma unroll
                for (int qt = 0; qt < 2; qt++)
#pragma unroll
                    for (int r = 0; r < 4; r++) {
                        float mt = lmax[qt][r];
#pragma unroll
                        for (int off = 1; off < 16; off <<= 1)
                            mt = fmaxf(mt, __shfl_xor(mt, off));
                        float mnew = fmaxf(mrow[qt][r], mt);
                        float al = exp2f(mrow[qt][r] - mnew);
                        mrow[qt][r] = mnew;
                        lsum[qt][r] *= al;
#pragma unroll
                        for (int dt = 0; dt < 4; dt++) o[qt][dt][r] *= al;
                    }
            }

            // exp2 + per-lane partial row-sum
#pragma unroll
            for (int qt = 0; qt < 2; qt++)
#pragma unroll
                for (int r = 0; r < 4; r++) {
                    float rs = 0.f;
#pragma unroll
                    for (int kt = 0; kt < 8; kt++) {
                        float p = exp2f(s[qt][kt][r] - mrow[qt][r]);
                        s[qt][kt][r] = p;
                        rs += p;
                    }
                    lsum[qt][r] += rs;
                }

            // P -> two padded LDS slabs (conflict-free) -> A-fragments
#pragma unroll
            for (int qt = 0; qt < 2; qt++)
#pragma unroll
                for (int kt = 0; kt < 8; kt++)
#pragma unroll
                    for (int r = 0; r < 4; r++)
                        plds[w][kt >> 2][qt * 16 + lg * 4 + r][(kt & 3) * 16 + lr] = (__bf16)s[qt][kt][r];

            // PV over 4 k-slots of 32 (dense Vf loads)
#pragma unroll
            for (int ks = 0; ks < 4; ks++) {
                bf16x8 vf[4];
#pragma unroll
                for (int dt = 0; dt < 4; dt++)
                    vf[dt] = *(const bf16x8*)(Vfp + ((((kt0 * 4 + ks) * 4) + dt) << 9) + lane * 8);
                bf16x8 pa[2];
#pragma unroll
                for (int qt = 0; qt < 2; qt++)
                    pa[qt] = *(const bf16x8*)&plds[w][ks >> 1][qt * 16 + lr][(ks & 1) * 32 + lg * 8];
#pragma unroll
                for (int qt = 0; qt < 2; qt++)
#pragma unroll
                    for (int dt = 0; dt < 4; dt++)
                        o[qt][dt] = MFMA16(pa[qt], vf[dt], o[qt][dt]);
            }
        };

        for (int kt0 = 0; kt0 < nkb - 1; ++kt0)
            tileBody(kt0, false);            // fully-unmasked fast path
        tileBody(nkb - 1, true);             // diagonal tile (masked)

        // final row-sum reduce (once per panel) + normalize + store
#pragma unroll
        for (int qt = 0; qt < 2; qt++)
#pragma unroll
            for (int r = 0; r < 4; r++) {
                float rs = lsum[qt][r];
#pragma unroll
                for (int off = 1; off < 16; off <<= 1)
                    rs += __shfl_xor(rs, off);
                lsum[qt][r] = 1.0f / rs;
            }
#pragma unroll
        for (int qt = 0; qt < 2; qt++)
#pragma unroll
            for (int dt = 0; dt < 4; dt++)
#pragma unroll
                for (int r = 0; r < 4; r++) {
                    int qq = qrow0 + qt * 16 + lg * 4 + r;
                    int dd = dt * 16 + lr;
                    float val = o[qt][dt][r] * lsum[qt][r];
                    ATT[(size_t)(b_ * 2048 + qq) * 1024 + hh * 64 + dd] = (__bf16)val;
                }
    }
}

// ---------------- proj GEMM (m97 structure + XCD-chunked swizzle) ----------------
__global__ __launch_bounds__(256, 2) void proj_gemm(const __bf16* __restrict__ A,
                                                    const __bf16* __restrict__ W,
                                                    const float* __restrict__ bias,
                                                    float* __restrict__ out) {
    const int KD = 1024;
    __shared__ __align__(16) __bf16 As[128 * 32];
    __shared__ __align__(16) __bf16 Bs[128 * 32];
    const int tid = threadIdx.x;
    const int lane = tid & 63, w = tid >> 6;
    const int lr = lane & 15, lg = lane >> 4;
    const int orig = blockIdx.x;                       // 0..511
    const int wgid = (orig & 7) * 64 + (orig >> 3);
    const int row0 = (wgid & 63) * 128, col0 = (wgid >> 6) * 128;
    const int wrow = (w >> 1) * 64, wcol = (w & 1) * 64;
    f32x4 acc[4][4] = {};
    const int c0 = tid, c1 = tid + 256;
    const __bf16* ga0 = A + (size_t)(row0 + (c0 >> 2)) * KD + (c0 & 3) * 8;
    const __bf16* ga1 = A + (size_t)(row0 + (c1 >> 2)) * KD + (c1 & 3) * 8;
    const __bf16* gb0 = W + (size_t)(col0 + (c0 >> 2)) * KD + (c0 & 3) * 8;
    const __bf16* gb1 = W + (size_t)(col0 + (c1 >> 2)) * KD + (c1 & 3) * 8;
    for (int k0 = 0; k0 < KD; k0 += 32) {
        __syncthreads();
        GLD16(ga0 + k0, As + c0 * 8);
        GLD16(ga1 + k0, As + c1 * 8);
        GLD16(gb0 + k0, Bs + c0 * 8);
        GLD16(gb1 + k0, Bs + c1 * 8);
        __syncthreads();
        bf16x8 a[4], b[4];
#pragma unroll
        for (int mi = 0; mi < 4; mi++)
            a[mi] = *(const bf16x8*)&As[(wrow + mi * 16 + lr) * 32 + lg * 8];
#pragma unroll
        for (int ni = 0; ni < 4; ni++)
            b[ni] = *(const bf16x8*)&Bs[(wcol + ni * 16 + lr) * 32 + lg * 8];
#pragma unroll
        for (int mi = 0; mi < 4; mi++)
#pragma unroll
            for (int ni = 0; ni < 4; ni++)
                acc[mi][ni] = MFMA16(a[mi], b[ni], acc[mi][ni]);
    }
#pragma unroll
    for (int mi = 0; mi < 4; mi++)
#pragma unroll
        for (int ni = 0; ni < 4; ni++)
#pragma unroll
            for (int r = 0; r < 4; r++) {
                int m = row0 + wrow + mi * 16 + lg * 4 + r;
                int n = col0 + wcol + ni * 16 + lr;
                out[(size_t)m * 1024 + n] = acc[mi][ni][r] + bias[n];
            }
}

extern "C" void kernel_launch(void* const* d_in, const int* in_sizes, int n_in,
                              void* d_out, int out_size, void* d_ws, size_t ws_size,
                              hipStream_t stream) {
    const float* x      = (const float*)d_in[0];
    const float* qkv_w  = (const float*)d_in[1];
    const float* qkv_b  = (const float*)d_in[2];
    const float* proj_w = (const float*)d_in[3];
    const float* proj_b = (const float*)d_in[4];
    float* out = (float*)d_out;
    char* ws = (char*)d_ws;

    __bf16* xb    = (__bf16*)(ws);                         // 16 MB (reused as attb)
    __bf16* wqkv  = (__bf16*)(ws + 16777216);              //  6 MB
    __bf16* wproj = (__bf16*)(ws + 23068672);              //  2 MB
    __bf16* qb    = (__bf16*)(ws + 25165824);              // 16 MB
    __bf16* kfb   = (__bf16*)(ws + 41943040);              // 16 MB (fragment-native K)
    __bf16* vfb   = (__bf16*)(ws + 58720256);              // 16 MB (fragment-native V)
    __bf16* attb  = xb;

    cvt3_f32_bf16<<<2048, 256, 0, stream>>>(x, xb, 4 * 2048 * 1024,
                                            qkv_w, wqkv, 3072 * 1024,
                                            proj_w, wproj, 1024 * 1024);
    qkv_gemm<<<1536, 256, 0, stream>>>(xb, wqkv, qkv_b, qb, kfb, vfb);
    attn_kernel<<<512, 256, 0, stream>>>(qb, kfb, vfb, attb);
    proj_gemm<<<512, 256, 0, stream>>>(attb, wproj, proj_b, out);
}

// Round 20
// 199.495 us; speedup vs baseline: 1.1956x; 1.1956x over previous
//
#include <hip/hip_runtime.h>
#include <hip/hip_bf16.h>

typedef __bf16 bf16x8 __attribute__((ext_vector_type(8)));
typedef __bf16 bf16x4 __attribute__((ext_vector_type(4)));
typedef float  f32x4  __attribute__((ext_vector_type(4)));

#define MFMA16(a, b, c) __builtin_amdgcn_mfma_f32_16x16x32_bf16((a), (b), (c), 0, 0, 0)
#define GLD16(g, l)                                                              \
    __builtin_amdgcn_global_load_lds(                                            \
        (const __attribute__((address_space(1))) void*)(g),                      \
        (__attribute__((address_space(3))) void*)(l), 16, 0, 0)

// ------------- fused fp32 -> bf16 convert for all three tensors (1 launch) ------
__global__ __launch_bounds__(256) void cvt3_f32_bf16(const float* __restrict__ a, __bf16* __restrict__ oa, int na,
                                                     const float* __restrict__ b, __bf16* __restrict__ ob, int nb,
                                                     const float* __restrict__ c, __bf16* __restrict__ oc, int nc) {
    const int stride = gridDim.x * blockDim.x * 4;
    const int start = (blockIdx.x * blockDim.x + threadIdx.x) * 4;
    for (int i = start; i < na; i += stride) {
        float4 v = *(const float4*)(a + i);
        bf16x4 o; o[0] = (__bf16)v.x; o[1] = (__bf16)v.y; o[2] = (__bf16)v.z; o[3] = (__bf16)v.w;
        *(bf16x4*)(oa + i) = o;
    }
    for (int i = start; i < nb; i += stride) {
        float4 v = *(const float4*)(b + i);
        bf16x4 o; o[0] = (__bf16)v.x; o[1] = (__bf16)v.y; o[2] = (__bf16)v.z; o[3] = (__bf16)v.w;
        *(bf16x4*)(ob + i) = o;
    }
    for (int i = start; i < nc; i += stride) {
        float4 v = *(const float4*)(c + i);
        bf16x4 o; o[0] = (__bf16)v.x; o[1] = (__bf16)v.y; o[2] = (__bf16)v.z; o[3] = (__bf16)v.w;
        *(bf16x4*)(oc + i) = o;
    }
}

// ---------------- QKV GEMM (BK=64, both-sides XOR swizzle, halved barriers) ------
// m97 skeleton with BK=64 (16 barrier pairs instead of 32). LDS [128][64] per
// operand; linear gload_lds dest + pre-swizzled global source (unit^(row&7)) +
// matching XOR on ds_read -> 2 lanes/bank (free). Fragment-native K/V epilogues.
// Q pre-scaled by 0.125*log2(e) so attention uses exp2 directly.
__global__ __launch_bounds__(256, 2) void qkv_gemm(const __bf16* __restrict__ X,
                                                   const __bf16* __restrict__ W,
                                                   const float* __restrict__ bias,
                                                   __bf16* __restrict__ Qo,
                                                   __bf16* __restrict__ Kf,
                                                   __bf16* __restrict__ Vf) {
    const int KD = 1024;
    __shared__ __align__(16) char smem[34816];   // As 16K | Bs 16K ; V-epilogue reuses
    __bf16* As = (__bf16*)smem;                  // [128][64] swizzled
    __bf16* Bs = (__bf16*)(smem + 16384);
    const int tid = threadIdx.x;
    const int lane = tid & 63, w = tid >> 6;
    const int lr = lane & 15, lg = lane >> 4;
    const int orig = blockIdx.x;                       // 0..1535
    const int wgid = (orig & 7) * 192 + (orig >> 3);   // bijective (1536 % 8 == 0)
    const int row0 = (wgid & 63) * 128, col0 = (wgid >> 6) * 128;
    const int wrow = (w >> 1) * 64, wcol = (w & 1) * 64;
    f32x4 acc[4][4] = {};
    // staging: 4 chunks/thread/operand; chunk c: row=c>>3, src unit=(c&7)^(row&7)
    const __bf16* gaG[4];
    const __bf16* gbG[4];
#pragma unroll
    for (int i = 0; i < 4; i++) {
        int c = tid + i * 256, r = c >> 3, u = (c & 7) ^ (r & 7);
        gaG[i] = X + (size_t)(row0 + r) * KD + u * 8;
        gbG[i] = W + (size_t)(col0 + r) * KD + u * 8;
    }
    const int uX = lr & 7;                             // read-side XOR (row&7 == lr&7)
    for (int k0 = 0; k0 < KD; k0 += 64) {
        __syncthreads();
#pragma unroll
        for (int i = 0; i < 4; i++) GLD16(gaG[i] + k0, As + (tid + i * 256) * 8);
#pragma unroll
        for (int i = 0; i < 4; i++) GLD16(gbG[i] + k0, Bs + (tid + i * 256) * 8);
        __syncthreads();
        bf16x8 a[4][2], b[4][2];
#pragma unroll
        for (int ks = 0; ks < 2; ks++) {
            const int u = (ks * 4 + lg) ^ uX;
#pragma unroll
            for (int mi = 0; mi < 4; mi++)
                a[mi][ks] = *(const bf16x8*)&As[(wrow + mi * 16 + lr) * 64 + u * 8];
#pragma unroll
            for (int ni = 0; ni < 4; ni++)
                b[ni][ks] = *(const bf16x8*)&Bs[(wcol + ni * 16 + lr) * 64 + u * 8];
        }
#pragma unroll
        for (int ks = 0; ks < 2; ks++)
#pragma unroll
            for (int mi = 0; mi < 4; mi++)
#pragma unroll
                for (int ni = 0; ni < 4; ni++)
                    acc[mi][ni] = MFMA16(a[mi][ks], b[ni][ks], acc[mi][ni]);
    }

    if (col0 < 1024) {
        // Q section: direct stores, pre-scaled by 0.125*log2(e)
#pragma unroll
        for (int mi = 0; mi < 4; mi++)
#pragma unroll
            for (int ni = 0; ni < 4; ni++)
#pragma unroll
                for (int r = 0; r < 4; r++) {
                    int m = row0 + wrow + mi * 16 + lg * 4 + r;
                    int n = col0 + wcol + ni * 16 + lr;
                    float v = acc[mi][ni][r] + bias[n];
                    int b_ = m >> 11, t = m & 2047;
                    int c = n & 1023;
                    int bh = b_ * 16 + (c >> 6), d = c & 63;
                    Qo[(size_t)(bh * 2048 + t) * 64 + d] = (__bf16)(v * 0.18033688f);
                }
    } else if (col0 < 2048) {
        // K section: direct scatter to fragment-native Kf
#pragma unroll
        for (int mi = 0; mi < 4; mi++)
#pragma unroll
            for (int ni = 0; ni < 4; ni++)
#pragma unroll
                for (int r = 0; r < 4; r++) {
                    int m = row0 + wrow + mi * 16 + lg * 4 + r;
                    int n = col0 + wcol + ni * 16 + lr;
                    float v = acc[mi][ni][r] + bias[n];
                    int b_ = m >> 11, t = m & 2047;
                    int c = n & 1023;
                    int bh = b_ * 16 + (c >> 6), d = c & 63;
                    size_t flat = (((size_t)bh * 128 + (t >> 4)) * 2 + (d >> 5)) * 512
                                + (((d & 31) >> 3) * 16 + (t & 15)) * 8 + (d & 7);
                    Kf[flat] = (__bf16)v;
                }
    } else {
        // V section: LDS [ch][token] transpose -> coalesced 1KB stores to Vf
        __syncthreads();
        __bf16* vt = (__bf16*)smem;          // [128 ch][136] padded
#pragma unroll
        for (int mi = 0; mi < 4; mi++)
#pragma unroll
            for (int ni = 0; ni < 4; ni++) {
                int cl = wcol + ni * 16 + lr;
                int tl = wrow + mi * 16 + lg * 4;
                int n = col0 + cl;
                bf16x4 pk;
#pragma unroll
                for (int r = 0; r < 4; r++)
                    pk[r] = (__bf16)(acc[mi][ni][r] + bias[n]);
                *(bf16x4*)&vt[cl * 136 + tl] = pk;
            }
        __syncthreads();
        const int b_ = row0 >> 11, t_base = row0 & 2047;
        const int lane2 = tid & 63, w2 = tid >> 6;
        const int lr2 = lane2 & 15, lg2 = lane2 >> 4;
#pragma unroll
        for (int g = 0; g < 8; g++) {
            int group = g * 4 + w2;                      // 0..31
            int hh2 = group >> 4;
            int k32l = (group >> 2) & 3;
            int dt = group & 3;
            const __bf16* src = &vt[(hh2 * 64 + dt * 16 + lr2) * 136 + k32l * 32 + lg2 * 8];
            int c = (col0 & 1023) + hh2 * 64;
            int bh = b_ * 16 + (c >> 6);
            int kt32 = (t_base >> 5) + k32l;
            __bf16* dst = Vf + ((((size_t)bh * 64 + kt32) * 4 + dt) * 512) + lane2 * 8;
            *(bf16x8*)dst = *(const bf16x8*)src;
        }
    }
}

// ---------------- causal flash attention (r18 champion + exp2) -------------------
// 512 blocks x 4 waves = 2048 uniform independent waves; wave owns q-tile pair
// {idx, 63-idx} = 33 k-tiles of 64, dense fragment-native K/V loads, diagonal-only
// masking, defer-max, padded conflict-free P slab. exp2 throughout (log2e folded
// into the Q pre-scale). This is the measured 84.8us structure.
__global__ __launch_bounds__(256) void attn_kernel(const __bf16* __restrict__ Q,
                                                   const __bf16* __restrict__ Kf,
                                                   const __bf16* __restrict__ Vf,
                                                   __bf16* __restrict__ ATT) {
    const int T = 2048, D = 64;
    __shared__ __align__(16) __bf16 plds[4][32][68];  // padded: conflict-free
    const int lane = threadIdx.x & 63, w = threadIdx.x >> 6;
    const int lr = lane & 15, lg = lane >> 4;
    const int orig = blockIdx.x;
    const int wgid = (orig & 7) * 64 + (orig >> 3);   // bijective XCD swizzle
    const int bh = wgid >> 3;                 // 8 blocks per bh
    const int idx = (wgid & 7) * 4 + w;       // 0..31
    const int b_ = bh >> 4, hh = bh & 15;
    const __bf16* Qp  = Q  + (size_t)bh * T * D;
    const __bf16* Kfp = Kf + (size_t)bh * 131072;   // 128 kt16 x 2 dk x 512
    const __bf16* Vfp = Vf + (size_t)bh * 131072;   // 64 kt32 x 4 dt x 512

    for (int ph = 0; ph < 2; ++ph) {
        const int j = ph ? 63 - idx : idx;
        const int qrow0 = j * 32;
        bf16x8 qa[2][2];
#pragma unroll
        for (int qt = 0; qt < 2; qt++)
#pragma unroll
            for (int dk = 0; dk < 2; dk++)
                qa[qt][dk] = *(const bf16x8*)(Qp + (size_t)(qrow0 + qt * 16 + lr) * D + dk * 32 + lg * 8);

        float mrow[2][4], lsum[2][4];
#pragma unroll
        for (int qt = 0; qt < 2; qt++)
#pragma unroll
            for (int r = 0; r < 4; r++) { mrow[qt][r] = -1e30f; lsum[qt][r] = 0.f; }
        f32x4 o[2][4] = {};

        const int nkb = (j + 2) >> 1;

        auto tileBody = [&](int kt0, bool masked) {
            const int kb = kt0 * 64;
            bf16x8 kf[4][2];
#pragma unroll
            for (int kt = 0; kt < 4; kt++)
#pragma unroll
                for (int dk = 0; dk < 2; dk++)
                    kf[kt][dk] = *(const bf16x8*)(Kfp + (((kt0 * 4 + kt) * 2 + dk) << 9) + lane * 8);
            f32x4 s[2][4] = {};
#pragma unroll
            for (int qt = 0; qt < 2; qt++)
#pragma unroll
                for (int kt = 0; kt < 4; kt++)
#pragma unroll
                    for (int dk = 0; dk < 2; dk++)
                        s[qt][kt] = MFMA16(qa[qt][dk], kf[kt][dk], s[qt][kt]);

            // (mask only on diagonal tile) + per-lane local max
            float lmax[2][4];
            int flag = 0;
#pragma unroll
            for (int qt = 0; qt < 2; qt++)
#pragma unroll
                for (int r = 0; r < 4; r++) {
                    const int qq = qrow0 + qt * 16 + lg * 4 + r;
                    float mt = -1e30f;
#pragma unroll
                    for (int kt = 0; kt < 4; kt++) {
                        float v = s[qt][kt][r];
                        if (masked) v = (kb + kt * 16 + lr <= qq) ? v : -1e30f;
                        s[qt][kt][r] = v;
                        mt = fmaxf(mt, v);
                    }
                    lmax[qt][r] = mt;
                    flag |= (mt > mrow[qt][r] + 8.0f) ? 1 : 0;
                }

            // defer-max (T13): full reduce + rescale only when some row grew > 8
            if (__any(flag)) {
#pragma unroll
                for (int qt = 0; qt < 2; qt++)
#pragma unroll
                    for (int r = 0; r < 4; r++) {
                        float mt = lmax[qt][r];
#pragma unroll
                        for (int off = 1; off < 16; off <<= 1)
                            mt = fmaxf(mt, __shfl_xor(mt, off));
                        float mnew = fmaxf(mrow[qt][r], mt);
                        float al = exp2f(mrow[qt][r] - mnew);
                        mrow[qt][r] = mnew;
                        lsum[qt][r] *= al;
#pragma unroll
                        for (int dt = 0; dt < 4; dt++) o[qt][dt][r] *= al;
                    }
            }

            // exp2 + per-lane partial row-sum
#pragma unroll
            for (int qt = 0; qt < 2; qt++)
#pragma unroll
                for (int r = 0; r < 4; r++) {
                    float rs = 0.f;
#pragma unroll
                    for (int kt = 0; kt < 4; kt++) {
                        float p = exp2f(s[qt][kt][r] - mrow[qt][r]);
                        s[qt][kt][r] = p;
                        rs += p;
                    }
                    lsum[qt][r] += rs;
                }

            // P -> padded LDS slab (conflict-free) -> A-fragments
#pragma unroll
            for (int qt = 0; qt < 2; qt++)
#pragma unroll
                for (int kt = 0; kt < 4; kt++)
#pragma unroll
                    for (int r = 0; r < 4; r++)
                        plds[w][qt * 16 + lg * 4 + r][kt * 16 + lr] = (__bf16)s[qt][kt][r];

            bf16x8 pa[2][2];
#pragma unroll
            for (int qt = 0; qt < 2; qt++)
#pragma unroll
                for (int kh = 0; kh < 2; kh++)
                    pa[qt][kh] = *(const bf16x8*)&plds[w][qt * 16 + lr][kh * 32 + lg * 8];

#pragma unroll
            for (int kh = 0; kh < 2; kh++) {
                bf16x8 vf[4];
#pragma unroll
                for (int dt = 0; dt < 4; dt++)
                    vf[dt] = *(const bf16x8*)(Vfp + ((((kt0 * 2 + kh) * 4) + dt) << 9) + lane * 8);
#pragma unroll
                for (int qt = 0; qt < 2; qt++)
#pragma unroll
                    for (int dt = 0; dt < 4; dt++)
                        o[qt][dt] = MFMA16(pa[qt][kh], vf[dt], o[qt][dt]);
            }
        };

        for (int kt0 = 0; kt0 < nkb - 1; ++kt0)
            tileBody(kt0, false);            // fully-unmasked fast path
        tileBody(nkb - 1, true);             // diagonal tile (masked)

        // final row-sum reduce (once per panel) + normalize + store
#pragma unroll
        for (int qt = 0; qt < 2; qt++)
#pragma unroll
            for (int r = 0; r < 4; r++) {
                float rs = lsum[qt][r];
#pragma unroll
                for (int off = 1; off < 16; off <<= 1)
                    rs += __shfl_xor(rs, off);
                lsum[qt][r] = 1.0f / rs;
            }
#pragma unroll
        for (int qt = 0; qt < 2; qt++)
#pragma unroll
            for (int dt = 0; dt < 4; dt++)
#pragma unroll
                for (int r = 0; r < 4; r++) {
                    int qq = qrow0 + qt * 16 + lg * 4 + r;
                    int dd = dt * 16 + lr;
                    float val = o[qt][dt][r] * lsum[qt][r];
                    ATT[(size_t)(b_ * 2048 + qq) * 1024 + hh * 64 + dd] = (__bf16)val;
                }
    }
}

// ---------------- proj GEMM (BK=64, both-sides XOR swizzle) ----------------------
__global__ __launch_bounds__(256, 2) void proj_gemm(const __bf16* __restrict__ A,
                                                    const __bf16* __restrict__ W,
                                                    const float* __restrict__ bias,
                                                    float* __restrict__ out) {
    const int KD = 1024;
    __shared__ __align__(16) __bf16 As[128 * 64];
    __shared__ __align__(16) __bf16 Bs[128 * 64];
    const int tid = threadIdx.x;
    const int lane = tid & 63, w = tid >> 6;
    const int lr = lane & 15, lg = lane >> 4;
    const int orig = blockIdx.x;                       // 0..511
    const int wgid = (orig & 7) * 64 + (orig >> 3);
    const int row0 = (wgid & 63) * 128, col0 = (wgid >> 6) * 128;
    const int wrow = (w >> 1) * 64, wcol = (w & 1) * 64;
    f32x4 acc[4][4] = {};
    const __bf16* gaG[4];
    const __bf16* gbG[4];
#pragma unroll
    for (int i = 0; i < 4; i++) {
        int c = tid + i * 256, r = c >> 3, u = (c & 7) ^ (r & 7);
        gaG[i] = A + (size_t)(row0 + r) * KD + u * 8;
        gbG[i] = W + (size_t)(col0 + r) * KD + u * 8;
    }
    const int uX = lr & 7;
    for (int k0 = 0; k0 < KD; k0 += 64) {
        __syncthreads();
#pragma unroll
        for (int i = 0; i < 4; i++) GLD16(gaG[i] + k0, As + (tid + i * 256) * 8);
#pragma unroll
        for (int i = 0; i < 4; i++) GLD16(gbG[i] + k0, Bs + (tid + i * 256) * 8);
        __syncthreads();
        bf16x8 a[4][2], b[4][2];
#pragma unroll
        for (int ks = 0; ks < 2; ks++) {
            const int u = (ks * 4 + lg) ^ uX;
#pragma unroll
            for (int mi = 0; mi < 4; mi++)
                a[mi][ks] = *(const bf16x8*)&As[(wrow + mi * 16 + lr) * 64 + u * 8];
#pragma unroll
            for (int ni = 0; ni < 4; ni++)
                b[ni][ks] = *(const bf16x8*)&Bs[(wcol + ni * 16 + lr) * 64 + u * 8];
        }
#pragma unroll
        for (int ks = 0; ks < 2; ks++)
#pragma unroll
            for (int mi = 0; mi < 4; mi++)
#pragma unroll
                for (int ni = 0; ni < 4; ni++)
                    acc[mi][ni] = MFMA16(a[mi][ks], b[ni][ks], acc[mi][ni]);
    }
#pragma unroll
    for (int mi = 0; mi < 4; mi++)
#pragma unroll
        for (int ni = 0; ni < 4; ni++)
#pragma unroll
            for (int r = 0; r < 4; r++) {
                int m = row0 + wrow + mi * 16 + lg * 4 + r;
                int n = col0 + wcol + ni * 16 + lr;
                out[(size_t)m * 1024 + n] = acc[mi][ni][r] + bias[n];
            }
}

extern "C" void kernel_launch(void* const* d_in, const int* in_sizes, int n_in,
                              void* d_out, int out_size, void* d_ws, size_t ws_size,
                              hipStream_t stream) {
    const float* x      = (const float*)d_in[0];
    const float* qkv_w  = (const float*)d_in[1];
    const float* qkv_b  = (const float*)d_in[2];
    const float* proj_w = (const float*)d_in[3];
    const float* proj_b = (const float*)d_in[4];
    float* out = (float*)d_out;
    char* ws = (char*)d_ws;

    __bf16* xb    = (__bf16*)(ws);                         // 16 MB (reused as attb)
    __bf16* wqkv  = (__bf16*)(ws + 16777216);              //  6 MB
    __bf16* wproj = (__bf16*)(ws + 23068672);              //  2 MB
    __bf16* qb    = (__bf16*)(ws + 25165824);              // 16 MB
    __bf16* kfb   = (__bf16*)(ws + 41943040);              // 16 MB (fragment-native K)
    __bf16* vfb   = (__bf16*)(ws + 58720256);              // 16 MB (fragment-native V)
    __bf16* attb  = xb;

    cvt3_f32_bf16<<<2048, 256, 0, stream>>>(x, xb, 4 * 2048 * 1024,
                                            qkv_w, wqkv, 3072 * 1024,
                                            proj_w, wproj, 1024 * 1024);
    qkv_gemm<<<1536, 256, 0, stream>>>(xb, wqkv, qkv_b, qb, kfb, vfb);
    attn_kernel<<<512, 256, 0, stream>>>(qb, kfb, vfb, attb);
    proj_gemm<<<512, 256, 0, stream>>>(attb, wproj, proj_b, out);
}

// Round 21
// 190.084 us; speedup vs baseline: 1.2548x; 1.0495x over previous
//
#include <hip/hip_runtime.h>
#include <hip/hip_bf16.h>

typedef __bf16 bf16x8 __attribute__((ext_vector_type(8)));
typedef __bf16 bf16x4 __attribute__((ext_vector_type(4)));
typedef float  f32x4  __attribute__((ext_vector_type(4)));

#define MFMA16(a, b, c) __builtin_amdgcn_mfma_f32_16x16x32_bf16((a), (b), (c), 0, 0, 0)
#define GLD16(g, l)                                                              \
    __builtin_amdgcn_global_load_lds(                                            \
        (const __attribute__((address_space(1))) void*)(g),                      \
        (__attribute__((address_space(3))) void*)(l), 16, 0, 0)

// ------------- fused fp32 -> bf16 convert for all three tensors (1 launch) ------
__global__ __launch_bounds__(256) void cvt3_f32_bf16(const float* __restrict__ a, __bf16* __restrict__ oa, int na,
                                                     const float* __restrict__ b, __bf16* __restrict__ ob, int nb,
                                                     const float* __restrict__ c, __bf16* __restrict__ oc, int nc) {
    const int stride = gridDim.x * blockDim.x * 4;
    const int start = (blockIdx.x * blockDim.x + threadIdx.x) * 4;
    for (int i = start; i < na; i += stride) {
        float4 v = *(const float4*)(a + i);
        bf16x4 o; o[0] = (__bf16)v.x; o[1] = (__bf16)v.y; o[2] = (__bf16)v.z; o[3] = (__bf16)v.w;
        *(bf16x4*)(oa + i) = o;
    }
    for (int i = start; i < nb; i += stride) {
        float4 v = *(const float4*)(b + i);
        bf16x4 o; o[0] = (__bf16)v.x; o[1] = (__bf16)v.y; o[2] = (__bf16)v.z; o[3] = (__bf16)v.w;
        *(bf16x4*)(ob + i) = o;
    }
    for (int i = start; i < nc; i += stride) {
        float4 v = *(const float4*)(c + i);
        bf16x4 o; o[0] = (__bf16)v.x; o[1] = (__bf16)v.y; o[2] = (__bf16)v.z; o[3] = (__bf16)v.w;
        *(bf16x4*)(oc + i) = o;
    }
}

// ---------------- QKV GEMM (BK=64, both-sides XOR swizzle, halved barriers) ------
// Q pre-scaled by 0.125 (back to __expf in attention; exp2f regression reverted).
__global__ __launch_bounds__(256, 2) void qkv_gemm(const __bf16* __restrict__ X,
                                                   const __bf16* __restrict__ W,
                                                   const float* __restrict__ bias,
                                                   __bf16* __restrict__ Qo,
                                                   __bf16* __restrict__ Kf,
                                                   __bf16* __restrict__ Vf) {
    const int KD = 1024;
    __shared__ __align__(16) char smem[34816];   // As 16K | Bs 16K ; V-epilogue reuses
    __bf16* As = (__bf16*)smem;                  // [128][64] swizzled
    __bf16* Bs = (__bf16*)(smem + 16384);
    const int tid = threadIdx.x;
    const int lane = tid & 63, w = tid >> 6;
    const int lr = lane & 15, lg = lane >> 4;
    const int orig = blockIdx.x;                       // 0..1535
    const int wgid = (orig & 7) * 192 + (orig >> 3);   // bijective (1536 % 8 == 0)
    const int row0 = (wgid & 63) * 128, col0 = (wgid >> 6) * 128;
    const int wrow = (w >> 1) * 64, wcol = (w & 1) * 64;
    f32x4 acc[4][4] = {};
    const __bf16* gaG[4];
    const __bf16* gbG[4];
#pragma unroll
    for (int i = 0; i < 4; i++) {
        int c = tid + i * 256, r = c >> 3, u = (c & 7) ^ (r & 7);
        gaG[i] = X + (size_t)(row0 + r) * KD + u * 8;
        gbG[i] = W + (size_t)(col0 + r) * KD + u * 8;
    }
    const int uX = lr & 7;                             // read-side XOR (row&7 == lr&7)
    for (int k0 = 0; k0 < KD; k0 += 64) {
        __syncthreads();
#pragma unroll
        for (int i = 0; i < 4; i++) GLD16(gaG[i] + k0, As + (tid + i * 256) * 8);
#pragma unroll
        for (int i = 0; i < 4; i++) GLD16(gbG[i] + k0, Bs + (tid + i * 256) * 8);
        __syncthreads();
        bf16x8 a[4][2], b[4][2];
#pragma unroll
        for (int ks = 0; ks < 2; ks++) {
            const int u = (ks * 4 + lg) ^ uX;
#pragma unroll
            for (int mi = 0; mi < 4; mi++)
                a[mi][ks] = *(const bf16x8*)&As[(wrow + mi * 16 + lr) * 64 + u * 8];
#pragma unroll
            for (int ni = 0; ni < 4; ni++)
                b[ni][ks] = *(const bf16x8*)&Bs[(wcol + ni * 16 + lr) * 64 + u * 8];
        }
#pragma unroll
        for (int ks = 0; ks < 2; ks++)
#pragma unroll
            for (int mi = 0; mi < 4; mi++)
#pragma unroll
                for (int ni = 0; ni < 4; ni++)
                    acc[mi][ni] = MFMA16(a[mi][ks], b[ni][ks], acc[mi][ni]);
    }

    if (col0 < 1024) {
        // Q section: direct stores, pre-scaled by 0.125
#pragma unroll
        for (int mi = 0; mi < 4; mi++)
#pragma unroll
            for (int ni = 0; ni < 4; ni++)
#pragma unroll
                for (int r = 0; r < 4; r++) {
                    int m = row0 + wrow + mi * 16 + lg * 4 + r;
                    int n = col0 + wcol + ni * 16 + lr;
                    float v = acc[mi][ni][r] + bias[n];
                    int b_ = m >> 11, t = m & 2047;
                    int c = n & 1023;
                    int bh = b_ * 16 + (c >> 6), d = c & 63;
                    Qo[(size_t)(bh * 2048 + t) * 64 + d] = (__bf16)(v * 0.125f);
                }
    } else if (col0 < 2048) {
        // K section: direct scatter to fragment-native Kf
#pragma unroll
        for (int mi = 0; mi < 4; mi++)
#pragma unroll
            for (int ni = 0; ni < 4; ni++)
#pragma unroll
                for (int r = 0; r < 4; r++) {
                    int m = row0 + wrow + mi * 16 + lg * 4 + r;
                    int n = col0 + wcol + ni * 16 + lr;
                    float v = acc[mi][ni][r] + bias[n];
                    int b_ = m >> 11, t = m & 2047;
                    int c = n & 1023;
                    int bh = b_ * 16 + (c >> 6), d = c & 63;
                    size_t flat = (((size_t)bh * 128 + (t >> 4)) * 2 + (d >> 5)) * 512
                                + (((d & 31) >> 3) * 16 + (t & 15)) * 8 + (d & 7);
                    Kf[flat] = (__bf16)v;
                }
    } else {
        // V section: LDS [ch][token] transpose -> coalesced 1KB stores to Vf
        __syncthreads();
        __bf16* vt = (__bf16*)smem;          // [128 ch][136] padded
#pragma unroll
        for (int mi = 0; mi < 4; mi++)
#pragma unroll
            for (int ni = 0; ni < 4; ni++) {
                int cl = wcol + ni * 16 + lr;
                int tl = wrow + mi * 16 + lg * 4;
                int n = col0 + cl;
                bf16x4 pk;
#pragma unroll
                for (int r = 0; r < 4; r++)
                    pk[r] = (__bf16)(acc[mi][ni][r] + bias[n]);
                *(bf16x4*)&vt[cl * 136 + tl] = pk;
            }
        __syncthreads();
        const int b_ = row0 >> 11, t_base = row0 & 2047;
        const int lane2 = tid & 63, w2 = tid >> 6;
        const int lr2 = lane2 & 15, lg2 = lane2 >> 4;
#pragma unroll
        for (int g = 0; g < 8; g++) {
            int group = g * 4 + w2;                      // 0..31
            int hh2 = group >> 4;
            int k32l = (group >> 2) & 3;
            int dt = group & 3;
            const __bf16* src = &vt[(hh2 * 64 + dt * 16 + lr2) * 136 + k32l * 32 + lg2 * 8];
            int c = (col0 & 1023) + hh2 * 64;
            int bh = b_ * 16 + (c >> 6);
            int kt32 = (t_base >> 5) + k32l;
            __bf16* dst = Vf + ((((size_t)bh * 64 + kt32) * 4 + dt) * 512) + lane2 * 8;
            *(bf16x8*)dst = *(const bf16x8*)src;
        }
    }
}

// ---------------- causal flash attention (r18 champion, exact) -------------------
// 512 blocks x 4 waves = 2048 uniform independent waves; wave owns q-tile pair
// {idx, 63-idx} = 33 k-tiles of 64, dense fragment-native K/V loads, diagonal-only
// masking, defer-max, padded conflict-free P slab, __expf. Measured 84.8us.
__global__ __launch_bounds__(256) void attn_kernel(const __bf16* __restrict__ Q,
                                                   const __bf16* __restrict__ Kf,
                                                   const __bf16* __restrict__ Vf,
                                                   __bf16* __restrict__ ATT) {
    const int T = 2048, D = 64;
    __shared__ __align__(16) __bf16 plds[4][32][68];  // padded: conflict-free
    const int lane = threadIdx.x & 63, w = threadIdx.x >> 6;
    const int lr = lane & 15, lg = lane >> 4;
    const int orig = blockIdx.x;
    const int wgid = (orig & 7) * 64 + (orig >> 3);   // bijective XCD swizzle
    const int bh = wgid >> 3;                 // 8 blocks per bh
    const int idx = (wgid & 7) * 4 + w;       // 0..31
    const int b_ = bh >> 4, hh = bh & 15;
    const __bf16* Qp  = Q  + (size_t)bh * T * D;
    const __bf16* Kfp = Kf + (size_t)bh * 131072;   // 128 kt16 x 2 dk x 512
    const __bf16* Vfp = Vf + (size_t)bh * 131072;   // 64 kt32 x 4 dt x 512

    for (int ph = 0; ph < 2; ++ph) {
        const int j = ph ? 63 - idx : idx;
        const int qrow0 = j * 32;
        bf16x8 qa[2][2];
#pragma unroll
        for (int qt = 0; qt < 2; qt++)
#pragma unroll
            for (int dk = 0; dk < 2; dk++)
                qa[qt][dk] = *(const bf16x8*)(Qp + (size_t)(qrow0 + qt * 16 + lr) * D + dk * 32 + lg * 8);

        float mrow[2][4], lsum[2][4];
#pragma unroll
        for (int qt = 0; qt < 2; qt++)
#pragma unroll
            for (int r = 0; r < 4; r++) { mrow[qt][r] = -1e30f; lsum[qt][r] = 0.f; }
        f32x4 o[2][4] = {};

        const int nkb = (j + 2) >> 1;

        auto tileBody = [&](int kt0, bool masked) {
            const int kb = kt0 * 64;
            bf16x8 kf[4][2];
#pragma unroll
            for (int kt = 0; kt < 4; kt++)
#pragma unroll
                for (int dk = 0; dk < 2; dk++)
                    kf[kt][dk] = *(const bf16x8*)(Kfp + (((kt0 * 4 + kt) * 2 + dk) << 9) + lane * 8);
            f32x4 s[2][4] = {};
#pragma unroll
            for (int qt = 0; qt < 2; qt++)
#pragma unroll
                for (int kt = 0; kt < 4; kt++)
#pragma unroll
                    for (int dk = 0; dk < 2; dk++)
                        s[qt][kt] = MFMA16(qa[qt][dk], kf[kt][dk], s[qt][kt]);

            // (mask only on diagonal tile) + per-lane local max
            float lmax[2][4];
            int flag = 0;
#pragma unroll
            for (int qt = 0; qt < 2; qt++)
#pragma unroll
                for (int r = 0; r < 4; r++) {
                    const int qq = qrow0 + qt * 16 + lg * 4 + r;
                    float mt = -1e30f;
#pragma unroll
                    for (int kt = 0; kt < 4; kt++) {
                        float v = s[qt][kt][r];
                        if (masked) v = (kb + kt * 16 + lr <= qq) ? v : -1e30f;
                        s[qt][kt][r] = v;
                        mt = fmaxf(mt, v);
                    }
                    lmax[qt][r] = mt;
                    flag |= (mt > mrow[qt][r] + 8.0f) ? 1 : 0;
                }

            // defer-max (T13): full reduce + rescale only when some row grew > 8
            if (__any(flag)) {
#pragma unroll
                for (int qt = 0; qt < 2; qt++)
#pragma unroll
                    for (int r = 0; r < 4; r++) {
                        float mt = lmax[qt][r];
#pragma unroll
                        for (int off = 1; off < 16; off <<= 1)
                            mt = fmaxf(mt, __shfl_xor(mt, off));
                        float mnew = fmaxf(mrow[qt][r], mt);
                        float al = __expf(mrow[qt][r] - mnew);
                        mrow[qt][r] = mnew;
                        lsum[qt][r] *= al;
#pragma unroll
                        for (int dt = 0; dt < 4; dt++) o[qt][dt][r] *= al;
                    }
            }

            // exp + per-lane partial row-sum
#pragma unroll
            for (int qt = 0; qt < 2; qt++)
#pragma unroll
                for (int r = 0; r < 4; r++) {
                    float rs = 0.f;
#pragma unroll
                    for (int kt = 0; kt < 4; kt++) {
                        float p = __expf(s[qt][kt][r] - mrow[qt][r]);
                        s[qt][kt][r] = p;
                        rs += p;
                    }
                    lsum[qt][r] += rs;
                }

            // P -> padded LDS slab (conflict-free) -> A-fragments
#pragma unroll
            for (int qt = 0; qt < 2; qt++)
#pragma unroll
                for (int kt = 0; kt < 4; kt++)
#pragma unroll
                    for (int r = 0; r < 4; r++)
                        plds[w][qt * 16 + lg * 4 + r][kt * 16 + lr] = (__bf16)s[qt][kt][r];

            bf16x8 pa[2][2];
#pragma unroll
            for (int qt = 0; qt < 2; qt++)
#pragma unroll
                for (int kh = 0; kh < 2; kh++)
                    pa[qt][kh] = *(const bf16x8*)&plds[w][qt * 16 + lr][kh * 32 + lg * 8];

#pragma unroll
            for (int kh = 0; kh < 2; kh++) {
                bf16x8 vf[4];
#pragma unroll
                for (int dt = 0; dt < 4; dt++)
                    vf[dt] = *(const bf16x8*)(Vfp + ((((kt0 * 2 + kh) * 4) + dt) << 9) + lane * 8);
#pragma unroll
                for (int qt = 0; qt < 2; qt++)
#pragma unroll
                    for (int dt = 0; dt < 4; dt++)
                        o[qt][dt] = MFMA16(pa[qt][kh], vf[dt], o[qt][dt]);
            }
        };

        for (int kt0 = 0; kt0 < nkb - 1; ++kt0)
            tileBody(kt0, false);            // fully-unmasked fast path
        tileBody(nkb - 1, true);             // diagonal tile (masked)

        // final row-sum reduce (once per panel) + normalize + store
#pragma unroll
        for (int qt = 0; qt < 2; qt++)
#pragma unroll
            for (int r = 0; r < 4; r++) {
                float rs = lsum[qt][r];
#pragma unroll
                for (int off = 1; off < 16; off <<= 1)
                    rs += __shfl_xor(rs, off);
                lsum[qt][r] = 1.0f / rs;
            }
#pragma unroll
        for (int qt = 0; qt < 2; qt++)
#pragma unroll
            for (int dt = 0; dt < 4; dt++)
#pragma unroll
                for (int r = 0; r < 4; r++) {
                    int qq = qrow0 + qt * 16 + lg * 4 + r;
                    int dd = dt * 16 + lr;
                    float val = o[qt][dt][r] * lsum[qt][r];
                    ATT[(size_t)(b_ * 2048 + qq) * 1024 + hh * 64 + dd] = (__bf16)val;
                }
    }
}

// ---------------- proj GEMM (BK=64, both-sides XOR swizzle) ----------------------
__global__ __launch_bounds__(256, 2) void proj_gemm(const __bf16* __restrict__ A,
                                                    const __bf16* __restrict__ W,
                                                    const float* __restrict__ bias,
                                                    float* __restrict__ out) {
    const int KD = 1024;
    __shared__ __align__(16) __bf16 As[128 * 64];
    __shared__ __align__(16) __bf16 Bs[128 * 64];
    const int tid = threadIdx.x;
    const int lane = tid & 63, w = tid >> 6;
    const int lr = lane & 15, lg = lane >> 4;
    const int orig = blockIdx.x;                       // 0..511
    const int wgid = (orig & 7) * 64 + (orig >> 3);
    const int row0 = (wgid & 63) * 128, col0 = (wgid >> 6) * 128;
    const int wrow = (w >> 1) * 64, wcol = (w & 1) * 64;
    f32x4 acc[4][4] = {};
    const __bf16* gaG[4];
    const __bf16* gbG[4];
#pragma unroll
    for (int i = 0; i < 4; i++) {
        int c = tid + i * 256, r = c >> 3, u = (c & 7) ^ (r & 7);
        gaG[i] = A + (size_t)(row0 + r) * KD + u * 8;
        gbG[i] = W + (size_t)(col0 + r) * KD + u * 8;
    }
    const int uX = lr & 7;
    for (int k0 = 0; k0 < KD; k0 += 64) {
        __syncthreads();
#pragma unroll
        for (int i = 0; i < 4; i++) GLD16(gaG[i] + k0, As + (tid + i * 256) * 8);
#pragma unroll
        for (int i = 0; i < 4; i++) GLD16(gbG[i] + k0, Bs + (tid + i * 256) * 8);
        __syncthreads();
        bf16x8 a[4][2], b[4][2];
#pragma unroll
        for (int ks = 0; ks < 2; ks++) {
            const int u = (ks * 4 + lg) ^ uX;
#pragma unroll
            for (int mi = 0; mi < 4; mi++)
                a[mi][ks] = *(const bf16x8*)&As[(wrow + mi * 16 + lr) * 64 + u * 8];
#pragma unroll
            for (int ni = 0; ni < 4; ni++)
                b[ni][ks] = *(const bf16x8*)&Bs[(wcol + ni * 16 + lr) * 64 + u * 8];
        }
#pragma unroll
        for (int ks = 0; ks < 2; ks++)
#pragma unroll
            for (int mi = 0; mi < 4; mi++)
#pragma unroll
                for (int ni = 0; ni < 4; ni++)
                    acc[mi][ni] = MFMA16(a[mi][ks], b[ni][ks], acc[mi][ni]);
    }
#pragma unroll
    for (int mi = 0; mi < 4; mi++)
#pragma unroll
        for (int ni = 0; ni < 4; ni++)
#pragma unroll
            for (int r = 0; r < 4; r++) {
                int m = row0 + wrow + mi * 16 + lg * 4 + r;
                int n = col0 + wcol + ni * 16 + lr;
                out[(size_t)m * 1024 + n] = acc[mi][ni][r] + bias[n];
            }
}

extern "C" void kernel_launch(void* const* d_in, const int* in_sizes, int n_in,
                              void* d_out, int out_size, void* d_ws, size_t ws_size,
                              hipStream_t stream) {
    const float* x      = (const float*)d_in[0];
    const float* qkv_w  = (const float*)d_in[1];
    const float* qkv_b  = (const float*)d_in[2];
    const float* proj_w = (const float*)d_in[3];
    const float* proj_b = (const float*)d_in[4];
    float* out = (float*)d_out;
    char* ws = (char*)d_ws;

    __bf16* xb    = (__bf16*)(ws);                         // 16 MB (reused as attb)
    __bf16* wqkv  = (__bf16*)(ws + 16777216);              //  6 MB
    __bf16* wproj = (__bf16*)(ws + 23068672);              //  2 MB
    __bf16* qb    = (__bf16*)(ws + 25165824);              // 16 MB
    __bf16* kfb   = (__bf16*)(ws + 41943040);              // 16 MB (fragment-native K)
    __bf16* vfb   = (__bf16*)(ws + 58720256);              // 16 MB (fragment-native V)
    __bf16* attb  = xb;

    cvt3_f32_bf16<<<2048, 256, 0, stream>>>(x, xb, 4 * 2048 * 1024,
                                            qkv_w, wqkv, 3072 * 1024,
                                            proj_w, wproj, 1024 * 1024);
    qkv_gemm<<<1536, 256, 0, stream>>>(xb, wqkv, qkv_b, qb, kfb, vfb);
    attn_kernel<<<512, 256, 0, stream>>>(qb, kfb, vfb, attb);
    proj_gemm<<<512, 256, 0, stream>>>(attb, wproj, proj_b, out);
}